// Round 2
// baseline (288.025 us; speedup 1.0000x reference)
//
#include <hip/hip_runtime.h>

typedef __attribute__((ext_vector_type(8))) _Float16 f16x8;
typedef __attribute__((ext_vector_type(4))) float f32x4;

#define S4 0.35355339059327373f   /* 64^-0.25 */

static __device__ __forceinline__ ushort f2h(float f) {
  return __builtin_bit_cast(ushort, (_Float16)f);
}
static __device__ __forceinline__ float h2f(ushort u) {
  return (float)__builtin_bit_cast(_Float16, u);
}
static __device__ __forceinline__ float hlo(unsigned u) {
  return (float)__builtin_bit_cast(_Float16, (ushort)(u & 0xffffu));
}
static __device__ __forceinline__ float hhi(unsigned u) {
  return (float)__builtin_bit_cast(_Float16, (ushort)(u >> 16));
}

static __device__ __forceinline__ void gload16(const void* g, void* l) {
  __builtin_amdgcn_global_load_lds((const __attribute__((address_space(1))) void*)g,
                                   (__attribute__((address_space(3))) void*)l, 16, 0, 0);
}

// ---------------------------------------------------------------------------
// C[M,N] = A[M,K] @ B[N,K]^T (+ epilogue), fp16 inputs, fp32 accum.
// EPI 0: +bias[col], store fp16      (QKV projections)
// EPI 1: 0.0625*exp(acc - rowvec[row]) + 1e-4, store fp16   (phi)
// EPI 2: acc / rowvec[row], store fp16                      (attn)
// EPI 3: +bias[col], store fp32                             (out projection)
// headmode=1: per-z A offset = (z>>3)*sAz + (z&7)*64 (head-sliced columns)
// ---------------------------------------------------------------------------
template<int BM, int BN, int WR, int WC, int EPI>
__global__ __launch_bounds__(256) void gemm_bt(
    const ushort* __restrict__ A, const ushort* __restrict__ B,
    const float* __restrict__ bias, ushort* __restrict__ Cb,
    float* __restrict__ Cf, const float* __restrict__ rowvec,
    int K, int ldA, int ldB, int ldC, int Mz,
    long sAz, long sBz, long sCz, int headmode)
{
  constexpr int BK = 32;
  constexpr int WTM = BM / WR, WTN = BN / WC;
  constexpr int MI = WTM / 16, NI = WTN / 16;
  constexpr int STAGE = (BM + BN) * BK * 2;   // bytes

  __shared__ uint4 smem4[STAGE / 16];
  char* smem = (char*)smem4;
  ushort* As = (ushort*)smem;                 // [BM][32]
  ushort* Bs = (ushort*)(smem + BM * 64);     // [BN][32]

  const int tid = threadIdx.x;
  const int l = tid & 63, w = tid >> 6;
  const int wr = w / WC, wc = w % WC;
  const int lr = l & 15, lk = l >> 4;
  const int tm = blockIdx.x * BM, tn = blockIdx.y * BN;
  const int z = blockIdx.z;

  const ushort* Az = A + (headmode ? ((long)(z >> 3) * sAz + (long)(z & 7) * 64)
                                   : (long)z * sAz);
  const ushort* Bz = B + (long)z * sBz;
  const float* rv = (EPI == 1 || EPI == 2) ? (rowvec + (long)z * Mz) : nullptr;

  f32x4 acc[MI][NI];
#pragma unroll
  for (int i = 0; i < MI; ++i)
#pragma unroll
    for (int j = 0; j < NI; ++j) acc[i][j] = f32x4{0.f, 0.f, 0.f, 0.f};

  for (int k0 = 0; k0 < K; k0 += BK) {
    // ---- stage A and B tiles via global_load_lds (16B/lane) ----
#pragma unroll
    for (int s = 0; s < STAGE / 4096; ++s) {
      int idx = s * 4096 + w * 1024 + l * 16;   // byte within staged region
      char* ldst = smem + s * 4096 + w * 1024;  // wave-uniform base
      const ushort* src;
      if (idx < BM * 64) {
        int row = idx >> 6, off = (idx & 63) >> 1;
        src = Az + (long)(tm + row) * ldA + k0 + off;
      } else {
        int i2 = idx - BM * 64;
        int row = i2 >> 6, off = (i2 & 63) >> 1;
        src = Bz + (long)(tn + row) * ldB + k0 + off;
      }
      gload16(src, ldst);
    }
    __syncthreads();

    f16x8 af[MI], bfr[NI];
#pragma unroll
    for (int mi = 0; mi < MI; ++mi)
      af[mi] = *(const f16x8*)(As + (wr * WTM + mi * 16 + lr) * 32 + lk * 8);
#pragma unroll
    for (int ni = 0; ni < NI; ++ni)
      bfr[ni] = *(const f16x8*)(Bs + (wc * WTN + ni * 16 + lr) * 32 + lk * 8);
#pragma unroll
    for (int mi = 0; mi < MI; ++mi)
#pragma unroll
      for (int ni = 0; ni < NI; ++ni)
        acc[mi][ni] = __builtin_amdgcn_mfma_f32_16x16x32_f16(af[mi], bfr[ni], acc[mi][ni], 0, 0, 0);
    __syncthreads();
  }

  // ---- epilogue ----
#pragma unroll
  for (int mi = 0; mi < MI; ++mi) {
#pragma unroll
    for (int ni = 0; ni < NI; ++ni) {
#pragma unroll
      for (int j = 0; j < 4; ++j) {
        int row = tm + wr * WTM + mi * 16 + lk * 4 + j;
        int col = tn + wc * WTN + ni * 16 + lr;
        float v = acc[mi][ni][j];
        if (EPI == 0 || EPI == 3) v += bias[col];
        if (EPI == 1) v = 0.0625f * __expf(v - rv[row]) + 1e-4f;
        if (EPI == 2) v = v / rv[row];
        long cidx = (long)z * sCz + (long)row * ldC + col;
        if (EPI == 3) Cf[cidx] = v;
        else          Cb[cidx] = f2h(v);
      }
    }
  }
}

// fp32 -> fp16 convert (element groups of 4), optional scale
__global__ void cvt_k(const float* __restrict__ in, ushort* __restrict__ out,
                      int n4, float scale) {
  int i = blockIdx.x * blockDim.x + threadIdx.x;
  if (i >= n4) return;
  float4 v = ((const float4*)in)[i];
  ushort4 o;
  o.x = f2h(v.x * scale); o.y = f2h(v.y * scale);
  o.z = f2h(v.z * scale); o.w = f2h(v.w * scale);
  ((ushort4*)out)[i] = o;
}

// diag[(b*8+h)*8192+n] = 0.5 * 64^-0.5 * sum_d X[b,n,h*64+d]^2
__global__ __launch_bounds__(256) void diag_kern(const ushort* __restrict__ Xh,
                                                 float* __restrict__ dg) {
  const int idx = blockIdx.x * 256 + threadIdx.x;
  const int n = idx & 8191, bh = idx >> 13, h = bh & 7, b = bh >> 3;
  const ushort* row = Xh + ((long)(b * 8192 + n)) * 512 + h * 64;
  float s = 0.f;
#pragma unroll
  for (int d = 0; d < 64; d += 8) {
    uint4 u = *(const uint4*)&row[d];
    float x0 = hlo(u.x), x1 = hhi(u.x), x2 = hlo(u.y), x3 = hhi(u.y);
    float x4 = hlo(u.z), x5 = hhi(u.z), x6 = hlo(u.w), x7 = hhi(u.w);
    s += x0*x0 + x1*x1 + x2*x2 + x3*x3 + x4*x4 + x5*x5 + x6*x6 + x7*x7;
  }
  dg[idx] = 0.0625f * s;   // 0.5 * 0.125
}

// ksum[bh][m] += sum over 512 rows of Kp[bh][n][m]
__global__ __launch_bounds__(256) void ksum_k(const ushort* __restrict__ Kp,
                                              float* __restrict__ ksum) {
  const int bh = blockIdx.x, s = blockIdx.y;
  const ushort* base = Kp + (long)bh * 8192 * 256 + threadIdx.x;
  const long n0 = (long)s * 512;
  float a0 = 0, a1 = 0, a2 = 0, a3 = 0;
  for (int n = 0; n < 512; n += 4) {
    a0 += h2f(base[(n0 + n    ) * 256]);
    a1 += h2f(base[(n0 + n + 1) * 256]);
    a2 += h2f(base[(n0 + n + 2) * 256]);
    a3 += h2f(base[(n0 + n + 3) * 256]);
  }
  atomicAdd(&ksum[bh * 256 + threadIdx.x], (a0 + a1) + (a2 + a3));
}

// ctx partials: cp[s][bh][d][m] = sum over 256 rows of Kp[n,m]*V[n,d]
__global__ __launch_bounds__(256) void ctx_k(const ushort* __restrict__ Kp,
                                             const ushort* __restrict__ Vh,
                                             float* __restrict__ cp) {
  const int bh = blockIdx.x;   // 16
  const int s  = blockIdx.y;   // 32
  const int h = bh & 7, b = bh >> 3;
  const ushort* KpB = Kp + (long)bh * 8192 * 256;
  const ushort* VB  = Vh + (long)b * 8192 * 512 + h * 64;
  const int tid = threadIdx.x;
  const int mg = tid & 63;    // m base = mg*4
  const int dg = tid >> 6;    // d base = dg*16
  __shared__ alignas(16) ushort kls[32 * 256];
  __shared__ alignas(16) ushort vls[32 * 64];
  float acc[4][16];
#pragma unroll
  for (int i = 0; i < 4; ++i)
#pragma unroll
    for (int j = 0; j < 16; ++j) acc[i][j] = 0.f;

  for (int c = 0; c < 8; ++c) {
    int n0 = s * 256 + c * 32;
#pragma unroll
    for (int it = 0; it < 4; ++it) {
      int byte = tid * 16 + it * 4096;
      int r = byte >> 9, col = (byte & 511) >> 1;
      *(uint4*)&kls[r * 256 + col] = *(const uint4*)&KpB[(long)(n0 + r) * 256 + col];
    }
    {
      int byte = tid * 16;
      int r = byte >> 7, col = (byte & 127) >> 1;
      *(uint4*)&vls[r * 64 + col] = *(const uint4*)&VB[(long)(n0 + r) * 512 + col];
    }
    __syncthreads();
#pragma unroll 4
    for (int n = 0; n < 32; ++n) {
      float kp[4], vv[16];
      {
        uint2 u = *(const uint2*)&kls[n * 256 + mg * 4];
        kp[0] = hlo(u.x); kp[1] = hhi(u.x); kp[2] = hlo(u.y); kp[3] = hhi(u.y);
      }
      {
        const uint4* vp = (const uint4*)&vls[n * 64 + dg * 16];
        uint4 u0 = vp[0], u1 = vp[1];
        vv[0] = hlo(u0.x); vv[1] = hhi(u0.x); vv[2] = hlo(u0.y); vv[3] = hhi(u0.y);
        vv[4] = hlo(u0.z); vv[5] = hhi(u0.z); vv[6] = hlo(u0.w); vv[7] = hhi(u0.w);
        vv[8] = hlo(u1.x); vv[9] = hhi(u1.x); vv[10] = hlo(u1.y); vv[11] = hhi(u1.y);
        vv[12] = hlo(u1.z); vv[13] = hhi(u1.z); vv[14] = hlo(u1.w); vv[15] = hhi(u1.w);
      }
#pragma unroll
      for (int i = 0; i < 4; ++i)
#pragma unroll
        for (int j = 0; j < 16; ++j) acc[i][j] += kp[i] * vv[j];
    }
    __syncthreads();
  }
  float* out = cp + (long)(s * 16 + bh) * 64 * 256;
#pragma unroll
  for (int i = 0; i < 4; ++i)
#pragma unroll
    for (int j = 0; j < 16; ++j)
      out[(long)(dg * 16 + j) * 256 + mg * 4 + i] = acc[i][j];
}

// reduce 32 ctx partials -> fp16 ctx_t[bh][d][m]
__global__ __launch_bounds__(256) void ctxred_k(const float* __restrict__ cp,
                                                ushort* __restrict__ ctxb) {
  const int idx = blockIdx.x * 256 + threadIdx.x;   // 262144
  float a = 0.f;
#pragma unroll 8
  for (int s = 0; s < 32; ++s) a += cp[(long)s * 262144 + idx];
  ctxb[idx] = f2h(a);
}

// denom[bh*8192+n] = sum_m Qp[n,m] * ksum[bh][m]
__global__ __launch_bounds__(256) void denom_k(const ushort* __restrict__ Qp,
                                               const float* __restrict__ ksum,
                                               float* __restrict__ denom) {
  const int idx = blockIdx.x * 256 + threadIdx.x;
  const int bh = idx >> 13;
  __shared__ float ks[256];
  ks[threadIdx.x] = ksum[bh * 256 + threadIdx.x];
  __syncthreads();
  const ushort* row = Qp + (long)idx * 256;
  float acc = 0.f;
#pragma unroll 4
  for (int m = 0; m < 256; m += 8) {
    uint4 u = *(const uint4*)&row[m];
    acc += hlo(u.x) * ks[m]     + hhi(u.x) * ks[m + 1]
         + hlo(u.y) * ks[m + 2] + hhi(u.y) * ks[m + 3]
         + hlo(u.z) * ks[m + 4] + hhi(u.z) * ks[m + 5]
         + hlo(u.w) * ks[m + 6] + hhi(u.w) * ks[m + 7];
  }
  denom[idx] = acc;
}

extern "C" void kernel_launch(void* const* d_in, const int* in_sizes, int n_in,
                              void* d_out, int out_size, void* d_ws, size_t ws_size,
                              hipStream_t stream) {
  (void)in_sizes; (void)n_in; (void)out_size; (void)ws_size;
  const float* q  = (const float*)d_in[0];
  const float* k  = (const float*)d_in[1];
  const float* v  = (const float*)d_in[2];
  const float* wq = (const float*)d_in[3];
  const float* bq = (const float*)d_in[4];
  const float* wk = (const float*)d_in[5];
  const float* bk = (const float*)d_in[6];
  const float* wv = (const float*)d_in[7];
  const float* bv = (const float*)d_in[8];
  const float* wo = (const float*)d_in[9];
  const float* bo = (const float*)d_in[10];
  const float* pj = (const float*)d_in[11];

  char* ws = (char*)d_ws;
  ushort* qbf   = (ushort*)(ws + 0);
  ushort* kbf   = (ushort*)(ws + 16777216);
  ushort* vbf   = (ushort*)(ws + 33554432);
  ushort* attnR = (ushort*)(ws + 0);          // overlays qbf (dead after proj)
  float*  cpart = (float*)(ws + 16777216);    // overlays kbf/vbf (dead after proj)
  ushort* wqh   = (ushort*)(ws + 50331648);
  ushort* wkh   = (ushort*)(ws + 50855936);
  ushort* wvh   = (ushort*)(ws + 51380224);
  ushort* woh   = (ushort*)(ws + 51904512);
  ushort* pjh   = (ushort*)(ws + 52428800);
  ushort* Qh    = (ushort*)(ws + 52461568);
  ushort* Kh    = (ushort*)(ws + 69238784);
  ushort* Vh    = (ushort*)(ws + 86016000);
  ushort* Pbuf  = (ushort*)(ws + 102793216);  // Kp, then reused as Qp
  float*  diagQ = (float*)(ws + 169902080);
  float*  diagK = (float*)(ws + 170426368);
  float*  ksum  = (float*)(ws + 170950656);
  ushort* ctxb  = (ushort*)(ws + 170967040);
  float*  denom = (float*)(ws + 171491328);

  // 1. fp32 -> fp16 conversions (proj pre-scaled by 64^-0.25)
  cvt_k<<<8192, 256, 0, stream>>>(q, qbf, 2097152, 1.f);
  cvt_k<<<8192, 256, 0, stream>>>(k, kbf, 2097152, 1.f);
  cvt_k<<<8192, 256, 0, stream>>>(v, vbf, 2097152, 1.f);
  cvt_k<<<256, 256, 0, stream>>>(wq, wqh, 65536, 1.f);
  cvt_k<<<256, 256, 0, stream>>>(wk, wkh, 65536, 1.f);
  cvt_k<<<256, 256, 0, stream>>>(wv, wvh, 65536, 1.f);
  cvt_k<<<256, 256, 0, stream>>>(wo, woh, 65536, 1.f);
  cvt_k<<<16, 256, 0, stream>>>(pj, pjh, 4096, S4);

  // 2. Q/K/V projections (+bias) -> fp16 [16384,512]
  gemm_bt<128,128,2,2,0><<<dim3(128,4,1), 256, 0, stream>>>(
      qbf, wqh, bq, Qh, nullptr, nullptr, 512, 512, 512, 512, 0, 0L, 0L, 0L, 0);
  gemm_bt<128,128,2,2,0><<<dim3(128,4,1), 256, 0, stream>>>(
      kbf, wkh, bk, Kh, nullptr, nullptr, 512, 512, 512, 512, 0, 0L, 0L, 0L, 0);
  gemm_bt<128,128,2,2,0><<<dim3(128,4,1), 256, 0, stream>>>(
      vbf, wvh, bv, Vh, nullptr, nullptr, 512, 512, 512, 512, 0, 0L, 0L, 0L, 0);

  // 3. per-row diag
  diag_kern<<<512, 256, 0, stream>>>(Qh, diagQ);
  diag_kern<<<512, 256, 0, stream>>>(Kh, diagK);

  // 4. phi(K) -> Pbuf (Kp)
  gemm_bt<128,128,2,2,1><<<dim3(64,2,16), 256, 0, stream>>>(
      Kh, pjh, nullptr, Pbuf, nullptr, diagK, 64, 512, 64, 256, 8192,
      4194304L, 0L, 2097152L, 1);

  // 5. ksum = sum_n Kp
  hipMemsetAsync(ksum, 0, 16 * 256 * 4, stream);
  ksum_k<<<dim3(16,16), 256, 0, stream>>>(Pbuf, ksum);

  // 6. ctx = Kp^T @ V  (partials + reduce -> fp16 ctx_t[d][m])
  ctx_k<<<dim3(16,32), 256, 0, stream>>>(Pbuf, Vh, cpart);
  ctxred_k<<<1024, 256, 0, stream>>>(cpart, ctxb);

  // 7. phi(Q) -> Pbuf (Qp; Kp dead)
  gemm_bt<128,128,2,2,1><<<dim3(64,2,16), 256, 0, stream>>>(
      Qh, pjh, nullptr, Pbuf, nullptr, diagQ, 64, 512, 64, 256, 8192,
      4194304L, 0L, 2097152L, 1);

  // 8. denom = Qp . ksum
  denom_k<<<512, 256, 0, stream>>>(Pbuf, ksum, denom);

  // 9. attn = (Qp @ ctx) / denom -> fp16, written in "faithful reshape" layout
  gemm_bt<128,64,4,1,2><<<dim3(64,1,16), 256, 0, stream>>>(
      Pbuf, ctxb, nullptr, attnR, nullptr, denom, 256, 256, 256, 64, 8192,
      2097152L, 16384L, 524288L, 0);

  // 10. output projection (+bias) -> fp32 d_out
  gemm_bt<128,128,2,2,3><<<dim3(128,4,1), 256, 0, stream>>>(
      attnR, woh, bo, nullptr, (float*)d_out, nullptr, 512, 512, 512, 512, 0,
      0L, 0L, 0L, 0);
}

// Round 6
// 232.483 us; speedup vs baseline: 1.2389x; 1.2389x over previous
//
#include <hip/hip_runtime.h>

typedef __attribute__((ext_vector_type(8))) _Float16 f16x8;
typedef __attribute__((ext_vector_type(4))) float f32x4;

#define S4 0.35355339059327373f   /* 64^-0.25 */

static __device__ __forceinline__ ushort f2h(float f) {
  return __builtin_bit_cast(ushort, (_Float16)f);
}
static __device__ __forceinline__ float hlo(unsigned u) {
  return (float)__builtin_bit_cast(_Float16, (ushort)(u & 0xffffu));
}
static __device__ __forceinline__ float hhi(unsigned u) {
  return (float)__builtin_bit_cast(_Float16, (ushort)(u >> 16));
}

static __device__ __forceinline__ void gload16(const void* g, void* l) {
  __builtin_amdgcn_global_load_lds((const __attribute__((address_space(1))) void*)g,
                                   (__attribute__((address_space(3))) void*)l, 16, 0, 0);
}

// ---------------------------------------------------------------------------
// C[M,N] = A[M,K] @ B[N,K]^T (+ epilogue), fp16 in, fp32 accum.
// EPI 0: +bias[col] -> fp16                (Q/K projections; optional DIAG)
// EPI 1: 0.0625*exp(acc - rv[row]) + 1e-4 -> fp16   (phi Q, row-diag)
// EPI 2: acc / rv[row] -> fp16                      (attn)
// EPI 3: +bias[col] -> fp32                         (out projection)
// EPI 4: +bias[row] -> fp16 at Vt scatter layout    (V^T projection)
// EPI 5: raw fp32 store                             (ctx split-K partials)
// EPI 6: 0.0625*exp(acc - rv[col]) + 1e-4 -> fp16   (phi K^T, col-diag)
// ZMODE 0: Az=A+z*sAz, Bz=B+z*sBz
// ZMODE 1: A head-sliced: Az=A+(z>>3)*sAz+(z&7)*64
// ZMODE 2: B head-sliced: Bz=B+(z>>3)*sBz+(z&7)*64
// ZMODE 3: split-K: z=(kc*16+bh); +=bh*s?z + kc*1024 (elements along K)
// DIAG 1: also store dg[(b*8+head)*8192+nn] = 0.0625*sum_head(v^2)  (EPI 0)
// ---------------------------------------------------------------------------
template<int BM, int BN, int WR, int WC, int EPI, int ZMODE, int DIAG>
__global__ __launch_bounds__(256) void gemm_bt(
    const ushort* __restrict__ A, const ushort* __restrict__ B,
    const float* __restrict__ bias, ushort* __restrict__ Cb,
    float* __restrict__ Cf, const float* __restrict__ rv0,
    float* __restrict__ dg,
    int K, int ldA, int ldB, int ldC, int Mz,
    long sAz, long sBz, long sCz)
{
  constexpr int BK = 32;
  constexpr int WTM = BM / WR, WTN = BN / WC;
  constexpr int MI = WTM / 16, NI = WTN / 16;
  constexpr int STAGE = (BM + BN) * BK * 2;   // bytes

  __shared__ uint4 smem4[STAGE / 16];
  char* smem = (char*)smem4;
  ushort* As = (ushort*)smem;                 // [BM][32]
  ushort* Bs = (ushort*)(smem + BM * 64);     // [BN][32]

  const int tid = threadIdx.x;
  const int l = tid & 63, w = tid >> 6;
  const int wr = w / WC, wc = w % WC;
  const int lr = l & 15, lk = l >> 4;
  const int tm = blockIdx.x * BM, tn = blockIdx.y * BN;
  const int z = blockIdx.z;

  const ushort* Az = A;
  const ushort* Bz = B;
  if (ZMODE == 0) { Az += (long)z * sAz; Bz += (long)z * sBz; }
  if (ZMODE == 1) { Az += (long)(z >> 3) * sAz + (z & 7) * 64; Bz += (long)z * sBz; }
  if (ZMODE == 2) { Az += (long)z * sAz; Bz += (long)(z >> 3) * sBz + (z & 7) * 64; }
  if (ZMODE == 3) {
    Az += (long)(z & 15) * sAz + (long)(z >> 4) * 1024;
    Bz += (long)(z & 15) * sBz + (long)(z >> 4) * 1024;
  }
  const float* rv = (EPI == 1 || EPI == 2 || EPI == 6) ? (rv0 + (long)z * Mz) : nullptr;
  const long coff = (long)z * sCz;

  f32x4 acc[MI][NI];
#pragma unroll
  for (int i = 0; i < MI; ++i)
#pragma unroll
    for (int j = 0; j < NI; ++j) acc[i][j] = f32x4{0.f, 0.f, 0.f, 0.f};

  for (int k0 = 0; k0 < K; k0 += BK) {
    // ---- stage A and B tiles via global_load_lds (16B/lane) ----
#pragma unroll
    for (int s = 0; s < STAGE / 4096; ++s) {
      int idx = s * 4096 + w * 1024 + l * 16;   // byte within staged region
      char* ldst = smem + s * 4096 + w * 1024;  // wave-uniform base
      const ushort* src;
      if (idx < BM * 64) {
        int row = idx >> 6, off = (idx & 63) >> 1;
        src = Az + (long)(tm + row) * ldA + k0 + off;
      } else {
        int i2 = idx - BM * 64;
        int row = i2 >> 6, off = (i2 & 63) >> 1;
        src = Bz + (long)(tn + row) * ldB + k0 + off;
      }
      gload16(src, ldst);
    }
    __syncthreads();

    f16x8 af[MI], bfr[NI];
#pragma unroll
    for (int mi = 0; mi < MI; ++mi)
      af[mi] = *(const f16x8*)(As + (wr * WTM + mi * 16 + lr) * 32 + lk * 8);
#pragma unroll
    for (int ni = 0; ni < NI; ++ni)
      bfr[ni] = *(const f16x8*)(Bs + (wc * WTN + ni * 16 + lr) * 32 + lk * 8);
#pragma unroll
    for (int mi = 0; mi < MI; ++mi)
#pragma unroll
      for (int ni = 0; ni < NI; ++ni)
        acc[mi][ni] = __builtin_amdgcn_mfma_f32_16x16x32_f16(af[mi], bfr[ni], acc[mi][ni], 0, 0, 0);
    __syncthreads();
  }

  // ---- epilogue ----
#pragma unroll
  for (int mi = 0; mi < MI; ++mi) {
#pragma unroll
    for (int j = 0; j < 4; ++j) {
      const int row = tm + wr * WTM + mi * 16 + lk * 4 + j;
      float ds = 0.f;
#pragma unroll
      for (int ni = 0; ni < NI; ++ni) {
        const int col = tn + wc * WTN + ni * 16 + lr;
        float v = acc[mi][ni][j];
        if (EPI == 0 || EPI == 3) v += bias[col];
        if (EPI == 4) v += bias[row];
        if (EPI == 1) v = 0.0625f * __expf(v - rv[row]) + 1e-4f;
        if (EPI == 6) v = 0.0625f * __expf(v - rv[col]) + 1e-4f;
        if (EPI == 2) v = v / rv[row];
        if (DIAG) ds += v * v;
        if (EPI == 4) {
          const int b = col >> 13, nn = col & 8191;
          const int h = row >> 6, d = row & 63;
          Cb[(long)(b * 8 + h) * 524288 + (long)d * 8192 + nn] = f2h(v);
        } else if (EPI == 3) {
          Cf[coff + (long)row * ldC + col] = v;
        } else if (EPI == 5) {
          Cf[coff + (long)row * ldC + col] = v;
        } else {
          Cb[coff + (long)row * ldC + col] = f2h(v);
        }
      }
      if (DIAG) {
        ds += __shfl_xor(ds, 1, 64);
        ds += __shfl_xor(ds, 2, 64);
        ds += __shfl_xor(ds, 4, 64);
        ds += __shfl_xor(ds, 8, 64);
        if (lr == 0) {
          const int b = row >> 13, nn = row & 8191;
          const int head = (tn + wc * WTN) >> 6;
          dg[(long)(b * 8 + head) * 8192 + nn] = 0.0625f * ds;
        }
      }
    }
  }
}

// fp32 -> fp16 convert (element groups of 4), optional scale
__global__ void cvt_k(const float* __restrict__ in, ushort* __restrict__ out,
                      int n4, float scale) {
  int i = blockIdx.x * blockDim.x + threadIdx.x;
  if (i >= n4) return;
  float4 v = ((const float4*)in)[i];
  ushort4 o;
  o.x = f2h(v.x * scale); o.y = f2h(v.y * scale);
  o.z = f2h(v.z * scale); o.w = f2h(v.w * scale);
  ((ushort4*)out)[i] = o;
}

// ksum[r=bh*256+m] = sum_n KpT[r][n], coalesced rows, one wave per row
__global__ __launch_bounds__(256) void ksum_k(const ushort* __restrict__ KpT,
                                              float* __restrict__ ksum) {
  const int r = blockIdx.x * 4 + (threadIdx.x >> 6);
  const int l = threadIdx.x & 63;
  const ushort* base = KpT + (long)r * 8192 + l * 8;
  float s = 0.f;
#pragma unroll 4
  for (int it = 0; it < 16; ++it) {
    uint4 u = *(const uint4*)(base + it * 512);
    s += hlo(u.x) + hhi(u.x) + hlo(u.y) + hhi(u.y)
       + hlo(u.z) + hhi(u.z) + hlo(u.w) + hhi(u.w);
  }
#pragma unroll
  for (int off = 32; off; off >>= 1) s += __shfl_down(s, off, 64);
  if (l == 0) ksum[r] = s;
}

// reduce 8 ctx split-K partials -> fp16 ctx_t[bh][d][m]
__global__ __launch_bounds__(256) void ctxred_k(const float* __restrict__ cp,
                                                ushort* __restrict__ ctxb) {
  const int idx = blockIdx.x * 256 + threadIdx.x;   // 262144
  float a = 0.f;
#pragma unroll
  for (int s = 0; s < 8; ++s) a += cp[(long)s * 262144 + idx];
  ctxb[idx] = f2h(a);
}

// denom[bh*8192+n] = sum_m Qp[n,m] * ksum[bh][m]
__global__ __launch_bounds__(256) void denom_k(const ushort* __restrict__ Qp,
                                               const float* __restrict__ ksum,
                                               float* __restrict__ denom) {
  const int idx = blockIdx.x * 256 + threadIdx.x;
  const int bh = idx >> 13;
  __shared__ float ks[256];
  ks[threadIdx.x] = ksum[bh * 256 + threadIdx.x];
  __syncthreads();
  const ushort* row = Qp + (long)idx * 256;
  float acc = 0.f;
#pragma unroll 4
  for (int m = 0; m < 256; m += 8) {
    uint4 u = *(const uint4*)&row[m];
    acc += hlo(u.x) * ks[m]     + hhi(u.x) * ks[m + 1]
         + hlo(u.y) * ks[m + 2] + hhi(u.y) * ks[m + 3]
         + hlo(u.z) * ks[m + 4] + hhi(u.z) * ks[m + 5]
         + hlo(u.w) * ks[m + 6] + hhi(u.w) * ks[m + 7];
  }
  denom[idx] = acc;
}

extern "C" void kernel_launch(void* const* d_in, const int* in_sizes, int n_in,
                              void* d_out, int out_size, void* d_ws, size_t ws_size,
                              hipStream_t stream) {
  (void)in_sizes; (void)n_in; (void)out_size; (void)ws_size;
  const float* q  = (const float*)d_in[0];
  const float* k  = (const float*)d_in[1];
  const float* v  = (const float*)d_in[2];
  const float* wq = (const float*)d_in[3];
  const float* bq = (const float*)d_in[4];
  const float* wk = (const float*)d_in[5];
  const float* bk = (const float*)d_in[6];
  const float* wv = (const float*)d_in[7];
  const float* bv = (const float*)d_in[8];
  const float* wo = (const float*)d_in[9];
  const float* bo = (const float*)d_in[10];
  const float* pj = (const float*)d_in[11];

  char* ws = (char*)d_ws;
  ushort* qbf   = (ushort*)(ws + 0);
  ushort* kbf   = (ushort*)(ws + 16777216);
  ushort* vbf   = (ushort*)(ws + 33554432);
  ushort* attnR = (ushort*)(ws + 0);          // overlays qbf (dead after Q proj)
  float*  cpart = (float*)(ws + 16777216);    // overlays kbf (dead after K proj), 8 MB
  ushort* wqh   = (ushort*)(ws + 50331648);
  ushort* wkh   = (ushort*)(ws + 50855936);
  ushort* wvh   = (ushort*)(ws + 51380224);
  ushort* woh   = (ushort*)(ws + 51904512);
  ushort* pjh   = (ushort*)(ws + 52428800);
  ushort* Qh    = (ushort*)(ws + 52461568);   // [16384][512] fp16
  ushort* Kh    = (ushort*)(ws + 69238784);   // [16384][512] fp16
  ushort* Vt    = (ushort*)(ws + 86016000);   // [16][64][8192] fp16
  ushort* Pbuf  = (ushort*)(ws + 102793216);  // KpT [16][256][8192], later Qp [16][8192][256]
  float*  diagQ = (float*)(ws + 169902080);
  float*  diagK = (float*)(ws + 170426368);
  float*  ksum  = (float*)(ws + 170950656);
  ushort* ctxb  = (ushort*)(ws + 170967040);  // [16][64][256] fp16
  float*  denom = (float*)(ws + 171491328);

  // 1. fp32 -> fp16 conversions (proj pre-scaled by 64^-0.25)
  cvt_k<<<8192, 256, 0, stream>>>(q, qbf, 2097152, 1.f);
  cvt_k<<<8192, 256, 0, stream>>>(k, kbf, 2097152, 1.f);
  cvt_k<<<8192, 256, 0, stream>>>(v, vbf, 2097152, 1.f);
  cvt_k<<<256, 256, 0, stream>>>(wq, wqh, 65536, 1.f);
  cvt_k<<<256, 256, 0, stream>>>(wk, wkh, 65536, 1.f);
  cvt_k<<<256, 256, 0, stream>>>(wv, wvh, 65536, 1.f);
  cvt_k<<<256, 256, 0, stream>>>(wo, woh, 65536, 1.f);
  cvt_k<<<16, 256, 0, stream>>>(pj, pjh, 4096, S4);

  // 2. Q/K projections (+bias, fused diag) -> fp16 [16384,512]
  gemm_bt<128,128,2,2,0,0,1><<<dim3(128,4,1), 256, 0, stream>>>(
      qbf, wqh, bq, Qh, nullptr, nullptr, diagQ, 512, 512, 512, 512, 0, 0L, 0L, 0L);
  gemm_bt<128,128,2,2,0,0,1><<<dim3(128,4,1), 256, 0, stream>>>(
      kbf, wkh, bk, Kh, nullptr, nullptr, diagK, 512, 512, 512, 512, 0, 0L, 0L, 0L);

  // 3. V^T projection: C[e=512][n=16384] = WV @ v_in^T -> Vt[bh][d][n]
  gemm_bt<128,128,2,2,4,0,0><<<dim3(4,128,1), 256, 0, stream>>>(
      wvh, vbf, bv, Vt, nullptr, nullptr, nullptr, 512, 512, 512, 0, 0, 0L, 0L, 0L);

  // 4. phi(K)^T: C[m=256][n=8192] per bh -> KpT (col-diag epilogue)
  gemm_bt<128,128,2,2,6,2,0><<<dim3(2,64,16), 256, 0, stream>>>(
      pjh, Kh, nullptr, Pbuf, nullptr, diagK, nullptr, 64, 64, 512, 8192, 8192,
      0L, 4194304L, 2097152L);

  // 5. ksum = row sums of KpT
  ksum_k<<<1024, 256, 0, stream>>>(Pbuf, ksum);

  // 6. ctx: C[d=64][m=256] = Vt @ KpT^T, split-K x8 -> fp32 partials, reduce
  gemm_bt<64,128,2,2,5,3,0><<<dim3(1,2,128), 256, 0, stream>>>(
      Vt, Pbuf, nullptr, nullptr, cpart, nullptr, nullptr, 1024, 8192, 8192, 256, 0,
      524288L, 2097152L, 16384L);
  ctxred_k<<<1024, 256, 0, stream>>>(cpart, ctxb);

  // 7. phi(Q) -> Qp [bh][n][m] (overwrites KpT; after ksum+ctx reads)
  gemm_bt<128,128,2,2,1,1,0><<<dim3(64,2,16), 256, 0, stream>>>(
      Qh, pjh, nullptr, Pbuf, nullptr, diagQ, nullptr, 64, 512, 64, 256, 8192,
      4194304L, 0L, 2097152L);

  // 8. denom = Qp . ksum
  denom_k<<<512, 256, 0, stream>>>(Pbuf, ksum, denom);

  // 9. attn = (Qp @ ctx_t^T) / denom -> fp16, "faithful reshape" layout
  gemm_bt<128,64,4,1,2,0,0><<<dim3(64,1,16), 256, 0, stream>>>(
      Pbuf, ctxb, nullptr, attnR, nullptr, denom, nullptr, 256, 256, 256, 64, 8192,
      2097152L, 16384L, 524288L);

  // 10. output projection (+bias) -> fp32 d_out
  gemm_bt<128,128,2,2,3,0,0><<<dim3(128,4,1), 256, 0, stream>>>(
      attnR, woh, bo, nullptr, (float*)d_out, nullptr, nullptr, 512, 512, 512, 512, 0,
      0L, 0L, 0L);
}

// Round 7
// 201.425 us; speedup vs baseline: 1.4299x; 1.1542x over previous
//
#include <hip/hip_runtime.h>

typedef __attribute__((ext_vector_type(8))) _Float16 f16x8;
typedef __attribute__((ext_vector_type(4))) float f32x4;

#define S4 0.35355339059327373f   /* 64^-0.25 */

static __device__ __forceinline__ ushort f2h(float f) {
  return __builtin_bit_cast(ushort, (_Float16)f);
}

static __device__ __forceinline__ void gload16(const void* g, void* l) {
  __builtin_amdgcn_global_load_lds((const __attribute__((address_space(1))) void*)g,
                                   (__attribute__((address_space(3))) void*)l, 16, 0, 0);
}

static __device__ __forceinline__ void cvt_store8(ushort* dst, float4 a, float4 b) {
  f16x8 h;
  h[0] = (_Float16)a.x; h[1] = (_Float16)a.y; h[2] = (_Float16)a.z; h[3] = (_Float16)a.w;
  h[4] = (_Float16)b.x; h[5] = (_Float16)b.y; h[6] = (_Float16)b.z; h[7] = (_Float16)b.w;
  *(f16x8*)dst = h;
}

// ---------------------------------------------------------------------------
// C[M,N] = A[M,K] @ B[N,K]^T (+ epilogue), fp16 MFMA, fp32 accum.
// EPI 0: +bias[col] -> fp16                       (Q/K projections; DIAG)
// EPI 1: 0.0625*exp(acc - rv[row]) + 1e-4 -> fp16 (phi Q, row-diag)
// EPI 3: +bias[col] -> fp32                       (out projection)
// EPI 4: +bias[row] -> fp16 at Vt[80-row] scatter (V^T projection)
// EPI 5: raw fp32 store                           (ctx split-K partials)
// EPI 6: 0.0625*exp(acc - rv[col]) + 1e-4 -> fp16 (phi K^T, col-diag)
// EPI 7: col64 = denom; cols 0..63 /= denom -> fp16 (attn, fused denominator)
// ZMODE 0: Az=A+z*sAz, Bz=B+z*sBz
// ZMODE 1: A head-sliced: Az=A+(z>>3)*sAz+(z&7)*64
// ZMODE 2: B head-sliced: Bz=B+(z>>3)*sBz+(z&7)*64
// ZMODE 3: split-K: z=(kc*16+bh): +=(z&15)*s?z + (z>>4)*1024 along K
// DIAG 1: dg[(b*8+head)*8192+nn] = 0.0625*sum_head(v^2)  (EPI 0)
// AF32/BF32: that operand is fp32 in global; reg-staged + converted to fp16 LDS
// ---------------------------------------------------------------------------
template<int BM, int BN, int WR, int WC, int EPI, int ZMODE, int DIAG, int AF32, int BF32>
__global__ __launch_bounds__(256) void gemm_bt(
    const void* __restrict__ Av, const void* __restrict__ Bv,
    const float* __restrict__ bias, ushort* __restrict__ Cb,
    float* __restrict__ Cf, const float* __restrict__ rv0,
    float* __restrict__ dg,
    int K, int ldA, int ldB, int ldC, int Mz,
    long sAz, long sBz, long sCz)
{
  constexpr int BK = 32;
  constexpr int WTM = BM / WR, WTN = BN / WC;
  constexpr int MI = WTM / 16, NI = WTN / 16;
  constexpr int LDSB = (BM + BN) * 64;   // fp16 tile bytes in LDS

  __shared__ uint4 smem4[LDSB / 16];
  char* smem = (char*)smem4;
  ushort* As = (ushort*)smem;                 // [BM][32] fp16
  ushort* Bs = (ushort*)(smem + BM * 64);     // [BN][32] fp16

  const int tid = threadIdx.x;
  const int l = tid & 63, w = tid >> 6;
  const int wr = w / WC, wc = w % WC;
  const int lr = l & 15, lk = l >> 4;
  const int tm = blockIdx.x * BM, tn = blockIdx.y * BN;
  const int z = blockIdx.z;

  const ushort* Ah = (const ushort*)Av;
  const ushort* Bh = (const ushort*)Bv;
  const float*  Af = (const float*)Av;
  const float*  Bf = (const float*)Bv;
  long aoff = 0, boff = 0;
  if (ZMODE == 0) { aoff = (long)z * sAz; boff = (long)z * sBz; }
  if (ZMODE == 1) { aoff = (long)(z >> 3) * sAz + (z & 7) * 64; boff = (long)z * sBz; }
  if (ZMODE == 2) { aoff = (long)z * sAz; boff = (long)(z >> 3) * sBz + (z & 7) * 64; }
  if (ZMODE == 3) {
    aoff = (long)(z & 15) * sAz + (long)(z >> 4) * 1024;
    boff = (long)(z & 15) * sBz + (long)(z >> 4) * 1024;
  }
  Ah += aoff; Bh += boff; Af += aoff; Bf += boff;
  const float* rv = (EPI == 1 || EPI == 6) ? (rv0 + (long)z * Mz) : nullptr;
  const long coff = (long)z * sCz;

  f32x4 acc[MI][NI];
#pragma unroll
  for (int i = 0; i < MI; ++i)
#pragma unroll
    for (int j = 0; j < NI; ++j) acc[i][j] = f32x4{0.f, 0.f, 0.f, 0.f};

  for (int k0 = 0; k0 < K; k0 += BK) {
    // ---- stage A tile ----
    if constexpr (AF32) {
      const int ar = tid >> 1, ac = (tid & 1) * 16;
      const float* g = Af + (long)(tm + ar) * ldA + k0 + ac;
      float4 f0 = *(const float4*)(g);
      float4 f1 = *(const float4*)(g + 4);
      float4 f2 = *(const float4*)(g + 8);
      float4 f3 = *(const float4*)(g + 12);
      cvt_store8(As + ar * 32 + ac, f0, f1);
      cvt_store8(As + ar * 32 + ac + 8, f2, f3);
    } else {
      constexpr int AB = BM * 64;
#pragma unroll
      for (int s = 0; s < (AB + 4095) / 4096; ++s) {
        const int base = s * 4096 + w * 1024;
        if (base < AB) {
          const int idx = base + l * 16;
          gload16(Ah + (long)(tm + (idx >> 6)) * ldA + k0 + ((idx & 63) >> 1),
                  (char*)As + base);
        }
      }
    }
    // ---- stage B tile ----
    if constexpr (BF32) {
      const int br = tid >> 1, bc = (tid & 1) * 16;
      const float* g = Bf + (long)(tn + br) * ldB + k0 + bc;
      float4 f0 = *(const float4*)(g);
      float4 f1 = *(const float4*)(g + 4);
      float4 f2 = *(const float4*)(g + 8);
      float4 f3 = *(const float4*)(g + 12);
      cvt_store8(Bs + br * 32 + bc, f0, f1);
      cvt_store8(Bs + br * 32 + bc + 8, f2, f3);
    } else {
      constexpr int BB = BN * 64;
#pragma unroll
      for (int s = 0; s < (BB + 4095) / 4096; ++s) {
        const int base = s * 4096 + w * 1024;
        if (base < BB) {
          const int idx = base + l * 16;
          gload16(Bh + (long)(tn + (idx >> 6)) * ldB + k0 + ((idx & 63) >> 1),
                  (char*)Bs + base);
        }
      }
    }
    __syncthreads();

    f16x8 af[MI], bfr[NI];
#pragma unroll
    for (int mi = 0; mi < MI; ++mi)
      af[mi] = *(const f16x8*)(As + (wr * WTM + mi * 16 + lr) * 32 + lk * 8);
#pragma unroll
    for (int ni = 0; ni < NI; ++ni)
      bfr[ni] = *(const f16x8*)(Bs + (wc * WTN + ni * 16 + lr) * 32 + lk * 8);
#pragma unroll
    for (int mi = 0; mi < MI; ++mi)
#pragma unroll
      for (int ni = 0; ni < NI; ++ni)
        acc[mi][ni] = __builtin_amdgcn_mfma_f32_16x16x32_f16(af[mi], bfr[ni], acc[mi][ni], 0, 0, 0);
    __syncthreads();
  }

  // ---- epilogue ----
#pragma unroll
  for (int mi = 0; mi < MI; ++mi) {
#pragma unroll
    for (int j = 0; j < 4; ++j) {
      const int row = tm + wr * WTM + mi * 16 + lk * 4 + j;
      float ds = 0.f;
      float dv = 1.f;
      if (EPI == 7) dv = __shfl(acc[mi][NI - 1][j], (l & 48), 64);
#pragma unroll
      for (int ni = 0; ni < NI; ++ni) {
        if (EPI == 7 && ni == NI - 1) continue;   // col 64 = denom, not stored
        const int col = tn + wc * WTN + ni * 16 + lr;
        float v = acc[mi][ni][j];
        if (EPI == 0 || EPI == 3) v += bias[col];
        if (EPI == 4) v += bias[row];
        if (EPI == 1) v = 0.0625f * __expf(v - rv[row]) + 1e-4f;
        if (EPI == 6) v = 0.0625f * __expf(v - rv[col]) + 1e-4f;
        if (EPI == 7) v = v / dv;
        if (DIAG) ds += v * v;
        if (EPI == 4) {
          const int b = col >> 13, nn = col & 8191;
          const int h = row >> 6, d = row & 63;
          Cb[(long)(b * 8 + h) * 655360 + (long)d * 8192 + nn] = f2h(v);
        } else if (EPI == 3 || EPI == 5) {
          Cf[coff + (long)row * ldC + col] = v;
        } else {
          Cb[coff + (long)row * ldC + col] = f2h(v);
        }
      }
      if (DIAG) {
        ds += __shfl_xor(ds, 1, 64);
        ds += __shfl_xor(ds, 2, 64);
        ds += __shfl_xor(ds, 4, 64);
        ds += __shfl_xor(ds, 8, 64);
        if (lr == 0) {
          const int b = row >> 13, nn = row & 8191;
          const int head = (tn + wc * WTN) >> 6;
          dg[(long)(b * 8 + head) * 8192 + nn] = 0.0625f * ds;
        }
      }
    }
  }
}

// fp32 -> fp16 convert (element groups of 4), optional scale
__global__ void cvt_k(const float* __restrict__ in, ushort* __restrict__ out,
                      int n4, float scale) {
  int i = blockIdx.x * blockDim.x + threadIdx.x;
  if (i >= n4) return;
  float4 v = ((const float4*)in)[i];
  ushort4 o;
  o.x = f2h(v.x * scale); o.y = f2h(v.y * scale);
  o.z = f2h(v.z * scale); o.w = f2h(v.w * scale);
  ((ushort4*)out)[i] = o;
}

// fill Vt rows 64..79: row 64 = 1.0 (ones row -> ksum via ctx GEMM), 65..79 = 0
__global__ __launch_bounds__(256) void vtpad_k(ushort* __restrict__ Vt) {
  const int i = blockIdx.x * 256 + threadIdx.x;   // 262144
  const int bh = i >> 14, rem = i & 16383, r = rem >> 10, n8 = rem & 1023;
  const unsigned val = (r == 0) ? 0x3C003C00u : 0u;
  uint4 u; u.x = val; u.y = val; u.z = val; u.w = val;
  *(uint4*)(Vt + (long)bh * 655360 + (long)(64 + r) * 8192 + n8 * 8) = u;
}

// reduce 8 ctx split-K partials -> fp16 ctxb[bh][80][256] (row 64 = ksum)
__global__ __launch_bounds__(256) void ctxred_k(const float* __restrict__ cp,
                                                ushort* __restrict__ ctxb) {
  const int idx = blockIdx.x * 256 + threadIdx.x;   // 327680
  const int bh = idx / 20480, rem = idx % 20480;
  float a = 0.f;
#pragma unroll
  for (int kc = 0; kc < 8; ++kc) a += cp[(long)(kc * 16 + bh) * 20480 + rem];
  ctxb[idx] = f2h(a);
}

extern "C" void kernel_launch(void* const* d_in, const int* in_sizes, int n_in,
                              void* d_out, int out_size, void* d_ws, size_t ws_size,
                              hipStream_t stream) {
  (void)in_sizes; (void)n_in; (void)out_size; (void)ws_size;
  const float* q  = (const float*)d_in[0];
  const float* k  = (const float*)d_in[1];
  const float* v  = (const float*)d_in[2];
  const float* wq = (const float*)d_in[3];
  const float* bq = (const float*)d_in[4];
  const float* wk = (const float*)d_in[5];
  const float* bk = (const float*)d_in[6];
  const float* wv = (const float*)d_in[7];
  const float* bv = (const float*)d_in[8];
  const float* wo = (const float*)d_in[9];
  const float* bo = (const float*)d_in[10];
  const float* pj = (const float*)d_in[11];

  char* ws = (char*)d_ws;
  ushort* attnR = (ushort*)(ws + 0);          // [16][8192][64] fp16, 16.8 MB
  float*  cpart = (float*)(ws + 16777216);    // [128][80][256] fp32, 10.5 MB
  ushort* wqh   = (ushort*)(ws + 27262976);
  ushort* wkh   = (ushort*)(ws + 27787264);
  ushort* wvh   = (ushort*)(ws + 28311552);
  ushort* woh   = (ushort*)(ws + 28835840);
  ushort* pjh   = (ushort*)(ws + 29360128);
  ushort* Qh    = (ushort*)(ws + 29392896);   // [16384][512] fp16
  ushort* Kh    = (ushort*)(ws + 46170112);   // [16384][512] fp16
  ushort* Vt    = (ushort*)(ws + 62947328);   // [16][80][8192] fp16 (row64=1s)
  ushort* Pbuf  = (ushort*)(ws + 83918848);   // KpT [16][256][8192] -> Qp [16][8192][256]
  float*  diagQ = (float*)(ws + 151027712);
  float*  diagK = (float*)(ws + 151552000);
  ushort* ctxb  = (ushort*)(ws + 152076288);  // [16][80][256] fp16 (row64=ksum)

  // 1. small weight conversions + Vt pad rows
  cvt_k<<<256, 256, 0, stream>>>(wq, wqh, 65536, 1.f);
  cvt_k<<<256, 256, 0, stream>>>(wk, wkh, 65536, 1.f);
  cvt_k<<<256, 256, 0, stream>>>(wv, wvh, 65536, 1.f);
  cvt_k<<<256, 256, 0, stream>>>(wo, woh, 65536, 1.f);
  cvt_k<<<16, 256, 0, stream>>>(pj, pjh, 4096, S4);
  vtpad_k<<<1024, 256, 0, stream>>>(Vt);

  // 2. Q/K projections (fp32 A reg-staged, +bias, fused diag) -> fp16
  gemm_bt<128,128,2,2,0,0,1,1,0><<<dim3(128,4,1), 256, 0, stream>>>(
      q, wqh, bq, Qh, nullptr, nullptr, diagQ, 512, 512, 512, 512, 0, 0L, 0L, 0L);
  gemm_bt<128,128,2,2,0,0,1,1,0><<<dim3(128,4,1), 256, 0, stream>>>(
      k, wkh, bk, Kh, nullptr, nullptr, diagK, 512, 512, 512, 512, 0, 0L, 0L, 0L);

  // 3. V^T projection (fp32 B reg-staged): C[e=512][n=16384] -> Vt[bh][d][n]
  gemm_bt<128,128,2,2,4,0,0,0,1><<<dim3(4,128,1), 256, 0, stream>>>(
      wvh, v, bv, Vt, nullptr, nullptr, nullptr, 512, 512, 512, 0, 0, 0L, 0L, 0L);

  // 4. phi(K)^T: C[m=256][n=8192] per bh -> KpT (col-diag epilogue)
  gemm_bt<128,128,2,2,6,2,0,0,0><<<dim3(2,64,16), 256, 0, stream>>>(
      pjh, Kh, nullptr, Pbuf, nullptr, diagK, nullptr, 64, 64, 512, 8192, 8192,
      0L, 4194304L, 2097152L);

  // 5. ctx (+ksum via ones row): C[80][m=256] = Vt @ KpT^T, split-K x8
  gemm_bt<80,128,1,4,5,3,0,0,0><<<dim3(1,2,128), 256, 0, stream>>>(
      Vt, Pbuf, nullptr, nullptr, cpart, nullptr, nullptr, 1024, 8192, 8192, 256, 0,
      655360L, 2097152L, 20480L);
  ctxred_k<<<1280, 256, 0, stream>>>(cpart, ctxb);

  // 6. phi(Q) -> Qp [bh][n][m] (overwrites KpT after ctx consumed it)
  gemm_bt<128,128,2,2,1,1,0,0,0><<<dim3(64,2,16), 256, 0, stream>>>(
      Qh, pjh, nullptr, Pbuf, nullptr, diagQ, nullptr, 64, 512, 64, 256, 8192,
      4194304L, 0L, 2097152L);

  // 7. attn (+fused denom via ksum row): C[n][80], cols0-63 /denom -> attnR
  gemm_bt<128,80,4,1,7,0,0,0,0><<<dim3(64,1,16), 256, 0, stream>>>(
      Pbuf, ctxb, nullptr, attnR, nullptr, nullptr, nullptr, 256, 256, 256, 64, 8192,
      2097152L, 20480L, 524288L);

  // 8. output projection (+bias) -> fp32 d_out
  gemm_bt<128,128,2,2,3,0,0,0,0><<<dim3(128,4,1), 256, 0, stream>>>(
      attnR, woh, bo, nullptr, (float*)d_out, nullptr, nullptr, 512, 512, 512, 512, 0,
      0L, 0L, 0L);
}